// Round 1
// baseline (364.061 us; speedup 1.0000x reference)
//
#include <hip/hip_runtime.h>
#include <hip/hip_bf16.h>

// CILRS head, MI355X. Strategy: bucket rows by command (compute ONLY the
// selected branch: 6x FLOP cut), bf16 MFMA 16x16x32 fused 3-layer tiles.
// ws layout (bytes):
//   0         spb    : B*128 bf16 sp-latent                (16,777,216)
//   16777216  perm   : (B+384) int32 grouped row indices   (   263,680)
//   17040896  cnt    : 20 ints: cnt[6], padoff[7], ctr2[6] (pad to 256)
//   17041152  Wsi2T  : [128][256] bf16
//   17106688  Wso1T  : [256][640] bf16
//   17434368  Wso2T  : [256][256] bf16
//   17565440  Wb1T   : [6][256][640] bf16
//   19531520  Wb2T   : [6][256][256] bf16   (end ~20.3 MB)

#define NB 65536

typedef __attribute__((ext_vector_type(8))) short short8;
typedef __attribute__((ext_vector_type(4))) float f32x4;
typedef unsigned short bhalf;

__device__ __forceinline__ bhalf f2b(float x) {
    union { float f; unsigned int u; } v; v.f = x;
    return (bhalf)((v.u + 0x7fffu + ((v.u >> 16) & 1u)) >> 16);   // RNE
}
__device__ __forceinline__ float b2f(bhalf u) {
    union { unsigned int u; float f; } v; v.u = ((unsigned int)u) << 16;
    return v.f;
}

__global__ void k_zero(int* c) { if (threadIdx.x < 20) c[threadIdx.x] = 0; }

// dst[b][n][k] = bf16(src[b][k][n])  (weights transposed so K is contiguous)
__global__ void k_transpose(const float* __restrict__ src, bhalf* __restrict__ dst,
                            int K, int N, int total) {
    int idx = blockIdx.x * 256 + threadIdx.x;
    if (idx >= total) return;
    int k = idx % K; int rem = idx / K; int n = rem % N; int b = rem / N;
    dst[idx] = f2b(src[(size_t)b * K * N + (size_t)k * N + n]);
}

__global__ void k_hist(const int* __restrict__ cmd, int* __restrict__ cnt) {
    int idx = blockIdx.x * 256 + threadIdx.x;
    int c = cmd[idx] - 1;
    int lane = threadIdx.x & 63;
    for (int g = 0; g < 6; ++g) {
        unsigned long long m = __ballot(c == g);
        if (m && lane == (__ffsll(m) - 1)) atomicAdd(&cnt[g], __popcll(m));
    }
}

__global__ void k_scan(int* cnt) {
    // cnt[0..5]=counts, cnt[6..12]=padoff (tile-padded prefix), cnt[13..18]=ctr2
    int off = 0;
    for (int g = 0; g < 6; ++g) {
        cnt[6 + g] = off;
        off += ((cnt[g] + 63) / 64) * 64;
        cnt[13 + g] = 0;
    }
    cnt[12] = off;
}

__global__ void k_scatter(const int* __restrict__ cmd, int* __restrict__ cnt,
                          int* __restrict__ perm) {
    int idx = blockIdx.x * 256 + threadIdx.x;
    int c = cmd[idx] - 1;
    int lane = threadIdx.x & 63;
    int* ctr2 = cnt + 13;
    const int* padoff = cnt + 6;
    for (int g = 0; g < 6; ++g) {
        unsigned long long m = __ballot(c == g);
        if (!m) continue;
        int leader = __ffsll(m) - 1;
        int base = 0;
        if (lane == leader) base = atomicAdd(&ctr2[g], __popcll(m));
        base = __shfl(base, leader);
        if (c == g) {
            int pos = base + __popcll(m & ((1ull << lane) - 1ull));
            perm[padoff[g] + pos] = idx;
        }
    }
}

// speed-latent: sp = relu(speed*Wsi1+bsi1) @ Wsi2 + bsi2, output bf16 [B,128]
__global__ __launch_bounds__(256) void k_prep(
    const float* __restrict__ speed, const float* __restrict__ Wsi1,
    const float* __restrict__ bsi1, const bhalf* __restrict__ Wsi2T,
    const float* __restrict__ bsi2, bhalf* __restrict__ spb) {
    __shared__ bhalf A[64 * 72];     // [64 rows][64 k] pad->72
    __shared__ bhalf BT[128 * 72];   // [128 n][64 k] pad->72
    const int t = threadIdx.x, lane = t & 63, wid = t >> 6;
    const int rbase = blockIdx.x * 64;
    const int wm = wid >> 1, wn = wid & 1;    // 2 waves M x 2 waves N
    f32x4 acc[2][4];
    for (int m = 0; m < 2; ++m) for (int n = 0; n < 4; ++n)
        for (int r = 0; r < 4; ++r) acc[m][n][r] = 0.f;
    const int ar = t >> 2, kp = (t & 3) * 16;
    const float s = speed[rbase + ar];
    for (int kc = 0; kc < 4; ++kc) {
        short8 w0, w1;
#pragma unroll
        for (int j = 0; j < 8; ++j) {
            int k = kc * 64 + kp + j;
            w0[j] = (short)f2b(fmaxf(fmaf(s, Wsi1[k], bsi1[k]), 0.f));
            w1[j] = (short)f2b(fmaxf(fmaf(s, Wsi1[k + 8], bsi1[k + 8]), 0.f));
        }
        *(short8*)&A[ar * 72 + kp] = w0;
        *(short8*)&A[ar * 72 + kp + 8] = w1;
#pragma unroll
        for (int j = 0; j < 4; ++j) {               // 1024 16B chunks of BT
            int ch = t + j * 256;
            int n2 = ch >> 3, ko = (ch & 7) * 8;
            *(short8*)&BT[n2 * 72 + ko] =
                *(const short8*)(Wsi2T + n2 * 256 + kc * 64 + ko);
        }
        __syncthreads();
#pragma unroll
        for (int ks = 0; ks < 2; ++ks) {
            short8 a[2], b[4];
#pragma unroll
            for (int m = 0; m < 2; ++m)
                a[m] = *(const short8*)&A[(wm * 32 + m * 16 + (lane & 15)) * 72 + ks * 32 + (lane >> 4) * 8];
#pragma unroll
            for (int n = 0; n < 4; ++n)
                b[n] = *(const short8*)&BT[(wn * 64 + n * 16 + (lane & 15)) * 72 + ks * 32 + (lane >> 4) * 8];
#pragma unroll
            for (int m = 0; m < 2; ++m)
#pragma unroll
                for (int n = 0; n < 4; ++n)
                    acc[m][n] = __builtin_amdgcn_mfma_f32_16x16x32_bf16(a[m], b[n], acc[m][n], 0, 0, 0);
        }
        __syncthreads();
    }
#pragma unroll
    for (int m = 0; m < 2; ++m)
#pragma unroll
    for (int n = 0; n < 4; ++n) {
        int col = wn * 64 + n * 16 + (lane & 15);
        float bias = bsi2[col];
#pragma unroll
        for (int r = 0; r < 4; ++r) {
            int row = rbase + wm * 32 + m * 16 + (lane >> 4) * 4 + r;
            spb[row * 128 + col] = f2b(acc[m][n][r] + bias);   // no relu
        }
    }
}

// Fused 3-layer head. 64 rows x 256 cols per block (4 waves of 64 cols),
// K1=640 (emb 512 f32 + sp 128 bf16), K2=256, layer3 SIMT (DOUT=1 or 3).
template <int DOUT, bool BRANCH>
__global__ __launch_bounds__(256) void k_head(
    const float* __restrict__ emb, const bhalf* __restrict__ spb,
    const bhalf* __restrict__ W1T, const float* __restrict__ b1,
    const bhalf* __restrict__ W2T, const float* __restrict__ b2,
    const float* __restrict__ W3, const float* __restrict__ b3,
    const int* __restrict__ cntbuf, const int* __restrict__ perm,
    float* __restrict__ outp) {
    __shared__ bhalf A[64 * 40];     // [64 rows][32 k] pad->40
    __shared__ bhalf BT[256 * 40];   // [256 n][32 k] pad->40
    __shared__ bhalf Y[64 * 264];    // [64 rows][256] pad->264
    const int t = threadIdx.x, lane = t & 63, wid = t >> 6;
    const int tstart = blockIdx.x * 64;
    int g = 0, gbase = 0, gcnt = NB;
    if (BRANCH) {
        const int* padoff = cntbuf + 6;
        if (tstart >= padoff[6]) return;
        while (padoff[g + 1] <= tstart) ++g;
        gbase = padoff[g]; gcnt = cntbuf[g];
        W1T += (size_t)g * 256 * 640; b1 += g * 256;
        W2T += (size_t)g * 256 * 256; b2 += g * 256;
        W3 += (size_t)g * 256 * DOUT; b3 += g * DOUT;
    }
    const int iA = t >> 2;                  // staging row (4 threads/row)
    int validA, rA;
    if (BRANCH) {
        int p = tstart + iA;
        validA = (p - gbase) < gcnt;
        rA = validA ? perm[p] : 0;          // clamp pads to a safe row
    } else { validA = 1; rA = tstart + iA; }

    f32x4 acc[4][4];
#pragma unroll
    for (int m = 0; m < 4; ++m) for (int n = 0; n < 4; ++n)
        for (int r = 0; r < 4; ++r) acc[m][n][r] = 0.f;

    // ---------------- layer 1: K = 640, 20 chunks of 32 ----------------
    for (int kc = 0; kc < 20; ++kc) {
        int kg = kc * 32 + (t & 3) * 8;
        short8 w;
        if (kc < 16) {   // from embedding (f32 -> bf16)
            const float4 f0 = *(const float4*)(emb + (size_t)rA * 512 + kg);
            const float4 f1 = *(const float4*)(emb + (size_t)rA * 512 + kg + 4);
            w[0] = (short)f2b(f0.x); w[1] = (short)f2b(f0.y);
            w[2] = (short)f2b(f0.z); w[3] = (short)f2b(f0.w);
            w[4] = (short)f2b(f1.x); w[5] = (short)f2b(f1.y);
            w[6] = (short)f2b(f1.z); w[7] = (short)f2b(f1.w);
        } else {         // from sp latent (already bf16)
            w = *(const short8*)(spb + (size_t)rA * 128 + (kg - 512));
        }
        *(short8*)&A[iA * 40 + (t & 3) * 8] = w;
#pragma unroll
        for (int j = 0; j < 4; ++j) {       // 1024 16B chunks of W1T slice
            int ch = t + j * 256;
            int n2 = ch >> 2, ko = (ch & 3) * 8;
            *(short8*)&BT[n2 * 40 + ko] =
                *(const short8*)(W1T + (size_t)n2 * 640 + kc * 32 + ko);
        }
        __syncthreads();
        short8 a[4], b[4];
#pragma unroll
        for (int m = 0; m < 4; ++m)
            a[m] = *(const short8*)&A[(m * 16 + (lane & 15)) * 40 + (lane >> 4) * 8];
#pragma unroll
        for (int n = 0; n < 4; ++n)
            b[n] = *(const short8*)&BT[(wid * 64 + n * 16 + (lane & 15)) * 40 + (lane >> 4) * 8];
#pragma unroll
        for (int m = 0; m < 4; ++m)
#pragma unroll
            for (int n = 0; n < 4; ++n)
                acc[m][n] = __builtin_amdgcn_mfma_f32_16x16x32_bf16(a[m], b[n], acc[m][n], 0, 0, 0);
        __syncthreads();
    }
    // epilogue 1: bias + relu -> Y (bf16)
#pragma unroll
    for (int m = 0; m < 4; ++m)
#pragma unroll
    for (int n = 0; n < 4; ++n) {
        int col = wid * 64 + n * 16 + (lane & 15);
        float bias = b1[col];
#pragma unroll
        for (int r = 0; r < 4; ++r) {
            int row = m * 16 + (lane >> 4) * 4 + r;
            Y[row * 264 + col] = f2b(fmaxf(acc[m][n][r] + bias, 0.f));
            acc[m][n][r] = 0.f;
        }
    }
    __syncthreads();
    // ---------------- layer 2: K = 256, 8 chunks of 32 ----------------
    for (int kc = 0; kc < 8; ++kc) {
#pragma unroll
        for (int j = 0; j < 4; ++j) {
            int ch = t + j * 256;
            int n2 = ch >> 2, ko = (ch & 3) * 8;
            *(short8*)&BT[n2 * 40 + ko] =
                *(const short8*)(W2T + (size_t)n2 * 256 + kc * 32 + ko);
        }
        __syncthreads();
        short8 a[4], b[4];
#pragma unroll
        for (int m = 0; m < 4; ++m)
            a[m] = *(const short8*)&Y[(m * 16 + (lane & 15)) * 264 + kc * 32 + (lane >> 4) * 8];
#pragma unroll
        for (int n = 0; n < 4; ++n)
            b[n] = *(const short8*)&BT[(wid * 64 + n * 16 + (lane & 15)) * 40 + (lane >> 4) * 8];
#pragma unroll
        for (int m = 0; m < 4; ++m)
#pragma unroll
            for (int n = 0; n < 4; ++n)
                acc[m][n] = __builtin_amdgcn_mfma_f32_16x16x32_bf16(a[m], b[n], acc[m][n], 0, 0, 0);
        __syncthreads();
    }
    // epilogue 2: bias + relu -> Y (overwrite; all reads done at loop-end sync)
#pragma unroll
    for (int m = 0; m < 4; ++m)
#pragma unroll
    for (int n = 0; n < 4; ++n) {
        int col = wid * 64 + n * 16 + (lane & 15);
        float bias = b2[col];
#pragma unroll
        for (int r = 0; r < 4; ++r) {
            int row = m * 16 + (lane >> 4) * 4 + r;
            Y[row * 264 + col] = f2b(fmaxf(acc[m][n][r] + bias, 0.f));
        }
    }
    __syncthreads();
    // ---------------- layer 3: SIMT dots ----------------
    if (DOUT == 3) {
        int o = t & 3;
        if (o < 3 && validA) {
            float accv = b3[o];
            for (int k = 0; k < 256; ++k)
                accv = fmaf(b2f(Y[iA * 264 + k]), W3[k * 3 + o], accv);
            outp[(size_t)rA * 3 + o] = 1.f / (1.f + expf(-accv));
        }
    } else {
        if (t < 64) {
            int r = tstart + t;
            float accv = b3[0];
            for (int k = 0; k < 256; ++k)
                accv = fmaf(b2f(Y[t * 264 + k]), W3[k], accv);
            outp[r] = accv;
        }
    }
}

extern "C" void kernel_launch(void* const* d_in, const int* in_sizes, int n_in,
                              void* d_out, int out_size, void* d_ws, size_t ws_size,
                              hipStream_t stream) {
    (void)in_sizes; (void)n_in; (void)out_size; (void)ws_size;
    const float* emb   = (const float*)d_in[0];
    const float* speed = (const float*)d_in[1];
    const int*   cmd   = (const int*)d_in[2];
    const float* Wsi1  = (const float*)d_in[3];
    const float* bsi1  = (const float*)d_in[4];
    const float* Wsi2  = (const float*)d_in[5];
    const float* bsi2  = (const float*)d_in[6];
    const float* Wso1  = (const float*)d_in[7];
    const float* bso1  = (const float*)d_in[8];
    const float* Wso2  = (const float*)d_in[9];
    const float* bso2  = (const float*)d_in[10];
    const float* Wso3  = (const float*)d_in[11];
    const float* bso3  = (const float*)d_in[12];
    const float* Wb1   = (const float*)d_in[13];
    const float* bb1   = (const float*)d_in[14];
    const float* Wb2   = (const float*)d_in[15];
    const float* bb2   = (const float*)d_in[16];
    const float* Wb3   = (const float*)d_in[17];
    const float* bb3   = (const float*)d_in[18];
    float* out = (float*)d_out;

    char* ws = (char*)d_ws;
    bhalf* spb   = (bhalf*)(ws);
    int*   perm  = (int*)(ws + 16777216);
    int*   cnt   = (int*)(ws + 17040896);
    bhalf* Wsi2T = (bhalf*)(ws + 17041152);
    bhalf* Wso1T = (bhalf*)(ws + 17106688);
    bhalf* Wso2T = (bhalf*)(ws + 17434368);
    bhalf* Wb1T  = (bhalf*)(ws + 17565440);
    bhalf* Wb2T  = (bhalf*)(ws + 19531520);

    k_zero<<<1, 64, 0, stream>>>(cnt);
    k_transpose<<<(256 * 128 + 255) / 256, 256, 0, stream>>>(Wsi2, Wsi2T, 256, 128, 256 * 128);
    k_transpose<<<(640 * 256 + 255) / 256, 256, 0, stream>>>(Wso1, Wso1T, 640, 256, 640 * 256);
    k_transpose<<<(256 * 256 + 255) / 256, 256, 0, stream>>>(Wso2, Wso2T, 256, 256, 256 * 256);
    k_transpose<<<(6 * 640 * 256 + 255) / 256, 256, 0, stream>>>(Wb1, Wb1T, 640, 256, 6 * 640 * 256);
    k_transpose<<<(6 * 256 * 256 + 255) / 256, 256, 0, stream>>>(Wb2, Wb2T, 256, 256, 6 * 256 * 256);
    k_prep<<<NB / 64, 256, 0, stream>>>(speed, Wsi1, bsi1, Wsi2T, bsi2, spb);
    k_hist<<<NB / 256, 256, 0, stream>>>(cmd, cnt);
    k_scan<<<1, 1, 0, stream>>>(cnt);
    k_scatter<<<NB / 256, 256, 0, stream>>>(cmd, cnt, perm);
    k_head<3, true><<<NB / 64 + 6, 256, 0, stream>>>(emb, spb, Wb1T, bb1, Wb2T, bb2,
                                                     Wb3, bb3, cnt, perm, out);
    k_head<1, false><<<NB / 64, 256, 0, stream>>>(emb, spb, Wso1T, bso1, Wso2T, bso2,
                                                  Wso3, bso3, cnt, perm, out + (size_t)NB * 3);
}

// Round 2
// 290.180 us; speedup vs baseline: 1.2546x; 1.2546x over previous
//
#include <hip/hip_runtime.h>

// CILRS head, MI355X round 2.
// - One merged head kernel (branch + speed), 64 rows x 256 cols per block.
// - LDS 53,248 B -> 3 blocks/CU (12 waves/CU).
// - Weight tiles staged via global_load_lds width=16 (pre-swizzled source,
//   XOR-swizzled ds_read: rule-21 both-sides discipline).
// - Layer 3 via MFMA (8 per wave) instead of 256-iter SIMT dot.
// ws layout (bytes):
//   0         spb    : B*128 bf16 sp-latent                (16,777,216)
//   16777216  perm   : (B+384) int32 grouped row indices   (   263,680)
//   17040896  cnt    : 20 ints: cnt[6], padoff[7], ctr2[6]
//   17041152  Wsi2T  : [128][256] bf16
//   17106688  Wso1T  : [256][640] bf16
//   17434368  Wso2T  : [256][256] bf16
//   17565440  Wb1T   : [6][256][640] bf16
//   19531520  Wb2T   : [6][256][256] bf16   (end 20,317,952)

#define NB 65536
#define NBRB 1030   // branch-region blocks = NB/64 + 6

typedef __attribute__((ext_vector_type(8))) short short8;
typedef __attribute__((ext_vector_type(4))) float f32x4;
typedef unsigned short bhalf;
typedef unsigned int u32;

__device__ __forceinline__ bhalf f2b(float x) {
    union { float f; u32 u; } v; v.f = x;
    return (bhalf)((v.u + 0x7fffu + ((v.u >> 16) & 1u)) >> 16);   // RNE
}
__device__ __forceinline__ float b2f(bhalf u) {
    union { u32 u; float f; } v; v.u = ((u32)u) << 16;
    return v.f;
}
__device__ __forceinline__ void gll16(const void* g, void* l) {
    __builtin_amdgcn_global_load_lds(
        (const __attribute__((address_space(1))) u32*)g,
        (__attribute__((address_space(3))) u32*)l, 16, 0, 0);
}
// 64B-row tiles (SA/SB): phys = row*64 + (cb ^ (((row>>1)&3)<<4))  -> 2-way max
__device__ __forceinline__ int sadr(int row, int cb) {
    return row * 64 + (cb ^ (((row >> 1) & 3) << 4));
}
// 512B-row tile (Y): phys = row*512 + (cb ^ ((row&7)<<4))          -> 2-way max
__device__ __forceinline__ int yadr(int row, int cb) {
    return row * 512 + (cb ^ ((row & 7) << 4));
}

__global__ void k_zero(int* c) { if (threadIdx.x < 20) c[threadIdx.x] = 0; }

// All weight transposes in one dispatch: dst[b][n][k] = bf16(src[b][k][n])
__global__ void k_wprep(const float* __restrict__ Wsi2, const float* __restrict__ Wso1,
                        const float* __restrict__ Wso2, const float* __restrict__ Wb1,
                        const float* __restrict__ Wb2,
                        bhalf* __restrict__ Wsi2T, bhalf* __restrict__ Wso1T,
                        bhalf* __restrict__ Wso2T, bhalf* __restrict__ Wb1T,
                        bhalf* __restrict__ Wb2T) {
    int idx = blockIdx.x * 256 + threadIdx.x;
    const float* s; bhalf* d; int K, N, li;
    if (idx < 32768)        { s = Wsi2; d = Wsi2T; K = 256; N = 128; li = idx; }
    else if (idx < 196608)  { s = Wso1; d = Wso1T; K = 640; N = 256; li = idx - 32768; }
    else if (idx < 262144)  { s = Wso2; d = Wso2T; K = 256; N = 256; li = idx - 196608; }
    else if (idx < 1245184) { s = Wb1;  d = Wb1T;  K = 640; N = 256; li = idx - 262144; }
    else if (idx < 1638400) { s = Wb2;  d = Wb2T;  K = 256; N = 256; li = idx - 1245184; }
    else return;
    int k = li % K; int rem = li / K; int n = rem % N; int b = rem / N;
    d[li] = f2b(s[(size_t)b * K * N + (size_t)k * N + n]);
}

__global__ void k_hist(const int* __restrict__ cmd, int* __restrict__ cnt) {
    int idx = blockIdx.x * 256 + threadIdx.x;
    int c = cmd[idx] - 1;
    int lane = threadIdx.x & 63;
    for (int g = 0; g < 6; ++g) {
        unsigned long long m = __ballot(c == g);
        if (m && lane == (__ffsll(m) - 1)) atomicAdd(&cnt[g], __popcll(m));
    }
}

__global__ void k_scan(int* cnt) {
    int off = 0;
    for (int g = 0; g < 6; ++g) {
        cnt[6 + g] = off;
        off += ((cnt[g] + 63) / 64) * 64;
        cnt[13 + g] = 0;
    }
    cnt[12] = off;
}

__global__ void k_scatter(const int* __restrict__ cmd, int* __restrict__ cnt,
                          int* __restrict__ perm) {
    int idx = blockIdx.x * 256 + threadIdx.x;
    int c = cmd[idx] - 1;
    int lane = threadIdx.x & 63;
    int* ctr2 = cnt + 13;
    const int* padoff = cnt + 6;
    for (int g = 0; g < 6; ++g) {
        unsigned long long m = __ballot(c == g);
        if (!m) continue;
        int leader = __ffsll(m) - 1;
        int base = 0;
        if (lane == leader) base = atomicAdd(&ctr2[g], __popcll(m));
        base = __shfl(base, leader);
        if (c == g) {
            int pos = base + __popcll(m & ((1ull << lane) - 1ull));
            perm[padoff[g] + pos] = idx;
        }
    }
}

// speed-latent: sp = relu(speed*Wsi1+bsi1) @ Wsi2 + bsi2, output bf16 [B,128]
__global__ __launch_bounds__(256) void k_prep(
    const float* __restrict__ speed, const float* __restrict__ Wsi1,
    const float* __restrict__ bsi1, const bhalf* __restrict__ Wsi2T,
    const float* __restrict__ bsi2, bhalf* __restrict__ spb) {
    __shared__ bhalf A[64 * 72];
    __shared__ bhalf BT[128 * 72];
    const int t = threadIdx.x, lane = t & 63, wid = t >> 6;
    const int rbase = blockIdx.x * 64;
    const int wm = wid >> 1, wn = wid & 1;
    f32x4 acc[2][4];
    for (int m = 0; m < 2; ++m) for (int n = 0; n < 4; ++n)
        for (int r = 0; r < 4; ++r) acc[m][n][r] = 0.f;
    const int ar = t >> 2, kp = (t & 3) * 16;
    const float s = speed[rbase + ar];
    for (int kc = 0; kc < 4; ++kc) {
        short8 w0, w1;
#pragma unroll
        for (int j = 0; j < 8; ++j) {
            int k = kc * 64 + kp + j;
            w0[j] = (short)f2b(fmaxf(fmaf(s, Wsi1[k], bsi1[k]), 0.f));
            w1[j] = (short)f2b(fmaxf(fmaf(s, Wsi1[k + 8], bsi1[k + 8]), 0.f));
        }
        *(short8*)&A[ar * 72 + kp] = w0;
        *(short8*)&A[ar * 72 + kp + 8] = w1;
#pragma unroll
        for (int j = 0; j < 4; ++j) {
            int ch = t + j * 256;
            int n2 = ch >> 3, ko = (ch & 7) * 8;
            *(short8*)&BT[n2 * 72 + ko] =
                *(const short8*)(Wsi2T + n2 * 256 + kc * 64 + ko);
        }
        __syncthreads();
#pragma unroll
        for (int ks = 0; ks < 2; ++ks) {
            short8 a[2], b[4];
#pragma unroll
            for (int m = 0; m < 2; ++m)
                a[m] = *(const short8*)&A[(wm * 32 + m * 16 + (lane & 15)) * 72 + ks * 32 + (lane >> 4) * 8];
#pragma unroll
            for (int n = 0; n < 4; ++n)
                b[n] = *(const short8*)&BT[(wn * 64 + n * 16 + (lane & 15)) * 72 + ks * 32 + (lane >> 4) * 8];
#pragma unroll
            for (int m = 0; m < 2; ++m)
#pragma unroll
                for (int n = 0; n < 4; ++n)
                    acc[m][n] = __builtin_amdgcn_mfma_f32_16x16x32_bf16(a[m], b[n], acc[m][n], 0, 0, 0);
        }
        __syncthreads();
    }
#pragma unroll
    for (int m = 0; m < 2; ++m)
#pragma unroll
    for (int n = 0; n < 4; ++n) {
        int col = wn * 64 + n * 16 + (lane & 15);
        float bias = bsi2[col];
#pragma unroll
        for (int r = 0; r < 4; ++r) {
            int row = rbase + wm * 32 + m * 16 + (lane >> 4) * 4 + r;
            spb[row * 128 + col] = f2b(acc[m][n][r] + bias);
        }
    }
}

// Merged fused 3-layer head: blockIdx < NBRB -> branch head (perm rows, DOUT=3,
// sigmoid), else speed head (identity rows, DOUT=1).
__global__ __launch_bounds__(256, 3) void k_head(
    const float* __restrict__ emb, const bhalf* __restrict__ spb,
    const bhalf* __restrict__ Wso1T, const float* __restrict__ bso1,
    const bhalf* __restrict__ Wso2T, const float* __restrict__ bso2,
    const float* __restrict__ Wso3, const float* __restrict__ bso3,
    const bhalf* __restrict__ Wb1T, const float* __restrict__ bb1,
    const bhalf* __restrict__ Wb2T, const float* __restrict__ bb2,
    const float* __restrict__ Wb3, const float* __restrict__ bb3,
    const int* __restrict__ cntbuf, const int* __restrict__ perm,
    float* __restrict__ out) {
    __shared__ __align__(16) char SA[4096];    // A tile  [64 rows][32 k] swz
    __shared__ __align__(16) char SB[16384];   // B tile  [256 n][32 k] swz
    __shared__ __align__(16) char Yb[32768];   // Y       [64 rows][256] swz
    const int t = threadIdx.x, lane = t & 63, wid = t >> 6;
    const bool isB = blockIdx.x < NBRB;
    const int* padoff = cntbuf + 6;
    int tstart, DOUT, gcnt, gbase;
    const bhalf *W1T, *W2T; const float *b1, *b2, *W3, *b3;
    if (isB) {
        tstart = blockIdx.x * 64;
        if (tstart >= padoff[6]) return;
        int g = 0;
        while (padoff[g + 1] <= tstart) ++g;
        gbase = padoff[g]; gcnt = cntbuf[g];
        W1T = Wb1T + (size_t)g * 256 * 640; b1 = bb1 + g * 256;
        W2T = Wb2T + (size_t)g * 256 * 256; b2 = bb2 + g * 256;
        W3  = Wb3 + (size_t)g * 256 * 3;    b3 = bb3 + g * 3;
        DOUT = 3;
    } else {
        tstart = (blockIdx.x - NBRB) * 64;
        gbase = 0; gcnt = NB;
        W1T = Wso1T; b1 = bso1; W2T = Wso2T; b2 = bso2; W3 = Wso3; b3 = bso3;
        DOUT = 1;
    }
    const int iA = t >> 2;
    const int pA = tstart + iA;
    int rA;
    if (isB) rA = ((pA - gbase) < gcnt) ? perm[pA] : 0;
    else     rA = pA;

    f32x4 acc[4][4];
#pragma unroll
    for (int m = 0; m < 4; ++m)
#pragma unroll
        for (int n = 0; n < 4; ++n)
#pragma unroll
            for (int r = 0; r < 4; ++r) acc[m][n][r] = 0.f;

    const int arow = lane & 15, koff = (lane >> 4) * 16;   // frag row / k-byte
    const int cbA = (t & 3) * 16;
    const int sAoff = sadr(iA, cbA);

    // ---------------- layer 1: K=640, 20 chunks of 32 ----------------
    for (int kc = 0; kc < 20; ++kc) {
        if (kc) __syncthreads();
        short8 w;
        int kg = kc * 32 + (t & 3) * 8;
        if (kc < 16) {
            const float4 f0 = *(const float4*)(emb + (size_t)rA * 512 + kg);
            const float4 f1 = *(const float4*)(emb + (size_t)rA * 512 + kg + 4);
            w[0] = (short)f2b(f0.x); w[1] = (short)f2b(f0.y);
            w[2] = (short)f2b(f0.z); w[3] = (short)f2b(f0.w);
            w[4] = (short)f2b(f1.x); w[5] = (short)f2b(f1.y);
            w[6] = (short)f2b(f1.z); w[7] = (short)f2b(f1.w);
        } else {
            w = *(const short8*)(spb + (size_t)rA * 128 + (kg - 512));
        }
        *(short8*)(SA + sAoff) = w;
#pragma unroll
        for (int j = 0; j < 4; ++j) {   // stage W1T chunk via global_load_lds
            int p = t * 16 + j * 4096;
            int row = p >> 6;
            int lcol = (p & 63) ^ (((row >> 1) & 3) << 4);
            gll16((const char*)W1T + (size_t)row * 1280 + kc * 64 + lcol, SB + p);
        }
        __syncthreads();
        short8 a[4], b[4];
#pragma unroll
        for (int m = 0; m < 4; ++m)
            a[m] = *(const short8*)(SA + sadr(m * 16 + arow, koff));
#pragma unroll
        for (int n = 0; n < 4; ++n)
            b[n] = *(const short8*)(SB + sadr(wid * 64 + n * 16 + arow, koff));
#pragma unroll
        for (int m = 0; m < 4; ++m)
#pragma unroll
            for (int n = 0; n < 4; ++n)
                acc[m][n] = __builtin_amdgcn_mfma_f32_16x16x32_bf16(a[m], b[n], acc[m][n], 0, 0, 0);
    }
    // epilogue 1: bias+relu -> Y (swizzled)
#pragma unroll
    for (int m = 0; m < 4; ++m)
#pragma unroll
    for (int n = 0; n < 4; ++n) {
        int col = wid * 64 + n * 16 + arow;
        float bias = b1[col];
#pragma unroll
        for (int r = 0; r < 4; ++r) {
            int row = m * 16 + (lane >> 4) * 4 + r;
            *(bhalf*)(Yb + yadr(row, 2 * col)) = f2b(fmaxf(acc[m][n][r] + bias, 0.f));
            acc[m][n][r] = 0.f;
        }
    }
    __syncthreads();
    // ---------------- layer 2: K=256, 8 chunks of 32 ----------------
    for (int kc = 0; kc < 8; ++kc) {
        if (kc) __syncthreads();
#pragma unroll
        for (int j = 0; j < 4; ++j) {
            int p = t * 16 + j * 4096;
            int row = p >> 6;
            int lcol = (p & 63) ^ (((row >> 1) & 3) << 4);
            gll16((const char*)W2T + (size_t)row * 512 + kc * 64 + lcol, SB + p);
        }
        __syncthreads();
        short8 a[4], b[4];
#pragma unroll
        for (int m = 0; m < 4; ++m)
            a[m] = *(const short8*)(Yb + yadr(m * 16 + arow, kc * 64 + koff));
#pragma unroll
        for (int n = 0; n < 4; ++n)
            b[n] = *(const short8*)(SB + sadr(wid * 64 + n * 16 + arow, koff));
#pragma unroll
        for (int m = 0; m < 4; ++m)
#pragma unroll
            for (int n = 0; n < 4; ++n)
                acc[m][n] = __builtin_amdgcn_mfma_f32_16x16x32_bf16(a[m], b[n], acc[m][n], 0, 0, 0);
    }
    __syncthreads();   // all layer-2 Y reads done before overwrite
    // epilogue 2: bias+relu -> Y
#pragma unroll
    for (int m = 0; m < 4; ++m)
#pragma unroll
    for (int n = 0; n < 4; ++n) {
        int col = wid * 64 + n * 16 + arow;
        float bias = b2[col];
#pragma unroll
        for (int r = 0; r < 4; ++r) {
            int row = m * 16 + (lane >> 4) * 4 + r;
            *(bhalf*)(Yb + yadr(row, 2 * col)) = f2b(fmaxf(acc[m][n][r] + bias, 0.f));
        }
    }
    __syncthreads();
    // ---------------- layer 3: MFMA, each wave one 16-row frag ----------------
    f32x4 z;
#pragma unroll
    for (int r = 0; r < 4; ++r) z[r] = 0.f;
    const int col3 = arow;
    for (int kc = 0; kc < 8; ++kc) {
        short8 a3 = *(const short8*)(Yb + yadr(wid * 16 + arow, kc * 64 + koff));
        short8 bw;
#pragma unroll
        for (int j = 0; j < 8; ++j) bw[j] = 0;
        if (col3 < DOUT) {
            int kb = kc * 32 + (lane >> 4) * 8;
#pragma unroll
            for (int j = 0; j < 8; ++j)
                bw[j] = (short)f2b(W3[(kb + j) * DOUT + col3]);
        }
        z = __builtin_amdgcn_mfma_f32_16x16x32_bf16(a3, bw, z, 0, 0, 0);
    }
    if (col3 < DOUT) {
        float bias = b3[col3];
#pragma unroll
        for (int rr = 0; rr < 4; ++rr) {
            int r = wid * 16 + (lane >> 4) * 4 + rr;
            int p = tstart + r;
            if ((p - gbase) < gcnt) {
                float v = z[rr] + bias;
                if (isB) {
                    int ro = perm[p];
                    out[(size_t)ro * 3 + col3] = 1.f / (1.f + __expf(-v));
                } else {
                    out[(size_t)NB * 3 + p] = v;
                }
            }
        }
    }
}

extern "C" void kernel_launch(void* const* d_in, const int* in_sizes, int n_in,
                              void* d_out, int out_size, void* d_ws, size_t ws_size,
                              hipStream_t stream) {
    (void)in_sizes; (void)n_in; (void)out_size; (void)ws_size;
    const float* emb   = (const float*)d_in[0];
    const float* speed = (const float*)d_in[1];
    const int*   cmd   = (const int*)d_in[2];
    const float* Wsi1  = (const float*)d_in[3];
    const float* bsi1  = (const float*)d_in[4];
    const float* Wsi2  = (const float*)d_in[5];
    const float* bsi2  = (const float*)d_in[6];
    const float* Wso1  = (const float*)d_in[7];
    const float* bso1  = (const float*)d_in[8];
    const float* Wso2  = (const float*)d_in[9];
    const float* bso2  = (const float*)d_in[10];
    const float* Wso3  = (const float*)d_in[11];
    const float* bso3  = (const float*)d_in[12];
    const float* Wb1   = (const float*)d_in[13];
    const float* bb1   = (const float*)d_in[14];
    const float* Wb2   = (const float*)d_in[15];
    const float* bb2   = (const float*)d_in[16];
    const float* Wb3   = (const float*)d_in[17];
    const float* bb3   = (const float*)d_in[18];
    float* out = (float*)d_out;

    char* ws = (char*)d_ws;
    bhalf* spb   = (bhalf*)(ws);
    int*   perm  = (int*)(ws + 16777216);
    int*   cnt   = (int*)(ws + 17040896);
    bhalf* Wsi2T = (bhalf*)(ws + 17041152);
    bhalf* Wso1T = (bhalf*)(ws + 17106688);
    bhalf* Wso2T = (bhalf*)(ws + 17434368);
    bhalf* Wb1T  = (bhalf*)(ws + 17565440);
    bhalf* Wb2T  = (bhalf*)(ws + 19531520);

    k_zero<<<1, 64, 0, stream>>>(cnt);
    k_wprep<<<6400, 256, 0, stream>>>(Wsi2, Wso1, Wso2, Wb1, Wb2,
                                      Wsi2T, Wso1T, Wso2T, Wb1T, Wb2T);
    k_prep<<<NB / 64, 256, 0, stream>>>(speed, Wsi1, bsi1, Wsi2T, bsi2, spb);
    k_hist<<<NB / 256, 256, 0, stream>>>(cmd, cnt);
    k_scan<<<1, 1, 0, stream>>>(cnt);
    k_scatter<<<NB / 256, 256, 0, stream>>>(cmd, cnt, perm);
    k_head<<<NBRB + NB / 64, 256, 0, stream>>>(emb, spb,
                                               Wso1T, bso1, Wso2T, bso2, Wso3, bso3,
                                               Wb1T, bb1, Wb2T, bb2, Wb3, bb3,
                                               cnt, perm, out);
}